// Round 8
// baseline (20079.510 us; speedup 1.0000x reference)
//
#include <hip/hip_runtime.h>
#include <stdint.h>

typedef unsigned short u16;
typedef unsigned int   u32;
typedef __attribute__((ext_vector_type(8))) short short8;   // 8 x bf16 fragment (4 VGPRs)
typedef __attribute__((ext_vector_type(4))) float f32x4;    // MFMA accumulator

#define B_TOT   2048
#define HID     512
#define T_FULL  128
#define ROWS    32                 // batch rows per GROUP (4 WGs)
#define NGRP    64
#define NWG     256                // 64 groups x 4 members -> all 256 CUs
#define THREADS 512                // 8 waves
#define NMEM    4

#define W0F_SZ  16384              // 32 ntiles * 64 lanes * 8
#define W1F_SZ  262144             // 32 nt * 16 kt * 64 * 8 (nt-major)
#define W3F_SZ  8192
#define WF_TOTAL (W0F_SZ + 2*W1F_SZ + W3F_SZ)   // 548864 u16 (~1.07 MB)
#define NFLAGS  (NGRP * 2 * NMEM)               // 512 u32
// ws layout: [wfrag u16 x WF_TOTAL][flags u32 x 512 (@ +4KB pad)][xbuf 2x64x4x8KB]

__device__ __forceinline__ u16 f2bf(float f){
  u32 u = __float_as_uint(f);
  u32 r = (u + 0x7FFFu + ((u >> 16) & 1u)) >> 16;   // RNE
  return (u16)r;
}

// LDS activation image: 32 rows x 512 cols bf16, row stride 512 (1024B),
// 16B chunks XOR-swizzled by (row&7). Note: member m's n-range [128m,128m+128)
// maps to chunks [16m,16m+16) per row (xor only permutes low 3 bits within an
// aligned 8-chunk sub-block) -> each member's slice is a contiguous 256B band/row.
__device__ __forceinline__ int lds_idx(int m, int k){
  int chunk = k >> 3;
  return m * 512 + ((chunk ^ (m & 7)) << 3) + (k & 7);
}

// ---------------- weight repack + flag zeroing ----------------
// B-frag 16x16x32: lane l holds B[k=(l>>4)*8+j][n=l&15], j=0..7.
__global__ void wm_repack(const float* __restrict__ W0, const float* __restrict__ W1,
                          const float* __restrict__ W2, const float* __restrict__ W3,
                          u16* __restrict__ wf)
{
  int idx = blockIdx.x * blockDim.x + threadIdx.x;
  if (idx >= WF_TOTAL){                  // zero the exchange flags (ws is 0xAA-poisoned)
    int fi = idx - WF_TOTAL;
    if (fi < NFLAGS) ((u32*)((char*)wf + WF_TOTAL*2 + 4096))[fi] = 0u;
    return;
  }
  int e = idx;
  if (e < W0F_SZ){                       // W0: 16x512, K padded to 32 with zeros
    int j = e & 7, l = (e >> 3) & 63, nt = e >> 9;
    int k = ((l >> 4) << 3) + j, n = (nt << 4) + (l & 15);
    wf[idx] = (k < 16) ? f2bf(W0[k * HID + n]) : (u16)0;
    return;
  }
  e -= W0F_SZ;
  if (e < W1F_SZ){                       // W1: 512x512, nt-major
    int j = e & 7, l = (e >> 3) & 63, rest = e >> 9, kt = rest & 15, nt = rest >> 4;
    int k = (kt << 5) + ((l >> 4) << 3) + j, n = (nt << 4) + (l & 15);
    wf[idx] = f2bf(W1[k * HID + n]);
    return;
  }
  e -= W1F_SZ;
  if (e < W1F_SZ){                       // W2: 512x512, nt-major
    int j = e & 7, l = (e >> 3) & 63, rest = e >> 9, kt = rest & 15, nt = rest >> 4;
    int k = (kt << 5) + ((l >> 4) << 3) + j, n = (nt << 4) + (l & 15);
    wf[idx] = f2bf(W2[k * HID + n]);
    return;
  }
  e -= W1F_SZ;
  {                                      // W3: 512x6, N padded to 16
    int j = e & 7, l = (e >> 3) & 63, kt = e >> 9;
    int k = (kt << 5) + ((l >> 4) << 3) + j, n = l & 15;
    wf[idx] = (n < 6) ? f2bf(W3[k * 6 + n]) : (u16)0;
  }
}

// ---------------- dynamics (fp32) ----------------
__device__ __forceinline__ void invert3(const float* a, float* inv){
  float d = a[0]*(a[4]*a[8]-a[5]*a[7]) - a[1]*(a[3]*a[8]-a[5]*a[6]) + a[2]*(a[3]*a[7]-a[4]*a[6]);
  float id = 1.0f / d;
  inv[0]=(a[4]*a[8]-a[5]*a[7])*id; inv[1]=(a[2]*a[7]-a[1]*a[8])*id; inv[2]=(a[1]*a[5]-a[2]*a[4])*id;
  inv[3]=(a[5]*a[6]-a[3]*a[8])*id; inv[4]=(a[0]*a[8]-a[2]*a[6])*id; inv[5]=(a[2]*a[3]-a[0]*a[5])*id;
  inv[6]=(a[3]*a[7]-a[4]*a[6])*id; inv[7]=(a[1]*a[6]-a[0]*a[7])*id; inv[8]=(a[0]*a[4]-a[1]*a[3])*id;
}

__device__ __forceinline__ void derivs(const float* x, const float* Fv,
                                       const float* I9, const float* Ii, float* dx)
{
  float V0=x[3], V1=x[4], V2=x[5];
  float phi=x[6], th=x[7], psi=x[8];
  float w0=x[9], w1=x[10], w2=x[11];
  float sph=__sinf(phi), cph=__cosf(phi);
  float sth=__sinf(th),  cth=__cosf(th);
  float sps=__sinf(psi), cps=__cosf(psi);
  float r00=cth*cps, r01=sph*sth*cps - cph*sps, r02=cph*sth*cps + sph*sps;
  float r10=cth*sps, r11=sph*sth*sps + cph*cps, r12=cph*sth*sps - sph*cps;
  float r20=-sth,    r21=sph*cth,               r22=cph*cth;
  dx[0]=r00*V0+r01*V1+r02*V2;
  dx[1]=r10*V0+r11*V1+r12*V2;
  dx[2]=r20*V0+r21*V1+r22*V2;
  const float invm = 1.0f/1.5f;
  dx[3]=Fv[0]*invm - (w1*V2 - w2*V1);
  dx[4]=Fv[1]*invm - (w2*V0 - w0*V2);
  dx[5]=Fv[2]*invm - (w0*V1 - w1*V0);
  float tth = sth / cth;
  float rc  = 1.0f / fmaxf(cth, 1e-6f);
  dx[6]= w0 + sph*tth*w1 + cph*tth*w2;
  dx[7]=      cph*w1     - sph*w2;
  dx[8]=      sph*rc*w1  + cph*rc*w2;
  float Iw0=I9[0]*w0+I9[1]*w1+I9[2]*w2;
  float Iw1=I9[3]*w0+I9[4]*w1+I9[5]*w2;
  float Iw2=I9[6]*w0+I9[7]*w1+I9[8]*w2;
  float c0=w1*Iw2-w2*Iw1, c1=w2*Iw0-w0*Iw2, c2=w0*Iw1-w1*Iw0;
  dx[9] = -(Ii[0]*c0+Ii[1]*c1+Ii[2]*c2);
  dx[10]= -(Ii[3]*c0+Ii[4]*c1+Ii[5]*c2);
  dx[11]= -(Ii[6]*c0+Ii[7]*c1+Ii[8]*c2);
}

__device__ __forceinline__ void rk4(float* X, const float* Fv, const float* I9, const float* Ii){
  float k1[12],k2[12],k3[12],k4[12],xt[12];
  derivs(X,Fv,I9,Ii,k1);
  #pragma unroll
  for (int c=0;c<12;++c) xt[c]=X[c]+0.005f*k1[c];
  derivs(xt,Fv,I9,Ii,k2);
  #pragma unroll
  for (int c=0;c<12;++c) xt[c]=X[c]+0.005f*k2[c];
  derivs(xt,Fv,I9,Ii,k3);
  #pragma unroll
  for (int c=0;c<12;++c) xt[c]=X[c]+0.01f*k3[c];
  derivs(xt,Fv,I9,Ii,k4);
  #pragma unroll
  for (int c=0;c<12;++c) X[c]+=(0.01f/6.0f)*(k1[c]+2.0f*k2[c]+2.0f*k3[c]+k4[c]);
}

__device__ __forceinline__ void build_input(u16* bufA, const float* X,
                                            const float* __restrict__ act,
                                            int b, int r, int t)
{
  float vin[16];
  vin[0]=X[0]*1.2732395447351628f;
  vin[1]=X[1]*0.5f;
  vin[2]=X[2]*1.2732395447351628f;
  vin[3]=X[3]*0.1f;
  vin[4]=X[4]*0.016666666666666666f;
  vin[5]=X[5]*0.016666666666666666f;
  #pragma unroll
  for (int c=6;c<12;++c) vin[c]=0.0f;
  #pragma unroll
  for (int a=0;a<4;++a)
    vin[12+a] = (act[(size_t)(b*4+a)*T_FULL + t] - 1500.0f) * 0.002f;
  #pragma unroll
  for (int p=0;p<16;++p){
    u32 pack = 0u;
    if (p < 8) pack = (u32)f2bf(vin[2*p]) | ((u32)f2bf(vin[2*p+1]) << 16);
    ((u32*)bufA)[lds_idx(r, 2*p) >> 1] = pack;
  }
}

// One 512-wide layer with 4-way N-split + slice exchange.
// Member computes its 8 n-tiles (1 per wave, 128 cols), writes its 256B/row band
// into bufOut AND to xgrp (global), then gathers the other 3 members' bands.
// Volatile (sc0/sc1 coherence-point) flag polling + __threadfence() release/acquire
// make this correct regardless of workgroup->XCD placement.
__device__ __forceinline__ void layer_ex(const u16* __restrict__ bufIn,
                                         u16* __restrict__ bufOut,
                                         const u16* __restrict__ wL,
                                         float bvv,
                                         u16* __restrict__ xgrp,     // 4 x 8KB slices
                                         u32* __restrict__ flagGrp,  // 4 flags
                                         u32 tag, int mem,
                                         int lane, int wave, int tid)
{
  const int lm = lane & 15, half = lane >> 4;
  const int m0 = lm, m1 = 16 + lm;
  const int sw0 = m0 & 7, sw1 = m1 & 7;
  const int nt = mem * 8 + wave;                  // global n-tile for this wave
  f32x4 acc0 = (f32x4)0.0f, acc1 = (f32x4)0.0f;
  const u16* wb = wL + (((size_t)nt * 16) * 64 + lane) * 8;
  #pragma unroll
  for (int kt = 0; kt < 16; ++kt){
    const int cb = (kt << 2) + half;
    short8 A0 = *(const short8*)(bufIn + m0*512 + ((cb ^ sw0) << 3));
    short8 A1 = *(const short8*)(bufIn + m1*512 + ((cb ^ sw1) << 3));
    short8 Bf = *(const short8*)(wb + ((size_t)kt << 9));
    acc0 = __builtin_amdgcn_mfma_f32_16x16x32_bf16(A0, Bf, acc0, 0, 0, 0);
    acc1 = __builtin_amdgcn_mfma_f32_16x16x32_bf16(A1, Bf, acc1, 0, 0, 0);
  }
  // epilogue: +bias, leaky, bf16 -> own band of bufOut (swizzled image)
  const int n = (nt << 4) + lm;
  #pragma unroll
  for (int reg = 0; reg < 4; ++reg){
    int r0 = (half << 2) + reg, r1 = 16 + r0;
    float v0 = acc0[reg] + bvv; v0 = (v0 >= 0.0f) ? v0 : 0.01f*v0;
    float v1 = acc1[reg] + bvv; v1 = (v1 >= 0.0f) ? v1 : 0.01f*v1;
    bufOut[lds_idx(r0, n)] = f2bf(v0);
    bufOut[lds_idx(r1, n)] = f2bf(v1);
  }
  __syncthreads();                                 // member's band complete in LDS
  // publish own 8KB band: 512 threads x 16B, straight copy of the swizzled image
  const int row = tid >> 4, c16 = tid & 15;
  {
    short8 v = *(const short8*)(bufOut + row*512 + (((mem << 4) + c16) << 3));
    *(short8*)(xgrp + ((size_t)mem << 12) + (size_t)tid * 8) = v;
  }
  __threadfence();                                 // stores visible at coherence point
  __syncthreads();                                 // ...for ALL threads of this WG
  if (tid == 0) *(volatile u32*)(flagGrp + mem) = tag;   // sc0/sc1 store -> L3
  // spin for the other 3 members (volatile = coherence-point reads, no cache thrash)
  #pragma unroll
  for (int o = 1; o < 4; ++o){
    const volatile u32* fp = (const volatile u32*)(flagGrp + ((mem + o) & 3));
    while (*fp < tag) __builtin_amdgcn_s_sleep(2);
  }
  __threadfence();                                 // acquire: invalidate stale cache
  #pragma unroll
  for (int o = 1; o < 4; ++o){
    const int mm = (mem + o) & 3;
    short8 v = *(const short8*)(xgrp + ((size_t)mm << 12) + (size_t)tid * 8);
    *(short8*)(bufOut + row*512 + (((mm << 4) + c16) << 3)) = v;
  }
  __syncthreads();                                 // full activation image ready
}

__global__ __launch_bounds__(THREADS, 2)
void wm_main(const float* __restrict__ x_t, const float* __restrict__ act,
             const float* __restrict__ Imat, const int* __restrict__ seqlen_p,
             const float* __restrict__ b0, const float* __restrict__ b1,
             const float* __restrict__ b2, const float* __restrict__ b3,
             const u16* __restrict__ wf, u32* __restrict__ flags,
             u16* __restrict__ xbuf, float* __restrict__ out)
{
  __shared__ u16 bufA[16384];           // 32 KB
  __shared__ u16 bufB[16384];           // 32 KB
  float* fscr = (float*)(bufA + 256);   // row-0 bytes 512..895: dead during tail

  const int tid  = threadIdx.x;
  const int lane = tid & 63;
  const int wave = tid >> 6;
  const int g    = blockIdx.x & 63;     // group
  const int mem  = blockIdx.x >> 6;     // member 0..3
  const int rowbase = g * ROWS;
  const int steps = seqlen_p[0] - 1;    // 127
  const int seqlen = steps + 1;

  const u16* w0f = wf;
  const u16* w1f = wf + W0F_SZ;
  const u16* w2f = w1f + W1F_SZ;
  const u16* w3f = w2f + W1F_SZ;
  u16* xg1 = xbuf + ((size_t)(0*NGRP + g) << 14);   // 4 slices x 4096 u16
  u16* xg2 = xbuf + ((size_t)(1*NGRP + g) << 14);
  u32* fl1 = flags + (g*2 + 0)*4;
  u32* fl2 = flags + (g*2 + 1)*4;

  float* outF = out;                                   // (B, 6, steps) fp32
  float* outX = out + (size_t)B_TOT * 6 * steps;       // (B, 12, seqlen) fp32

  // pre-loop register loads
  const int lm0 = lane & 15;
  short8 w0r[4];
  float bvL0[4];
  #pragma unroll
  for (int i=0;i<4;++i){
    w0r[i] = *(const short8*)(w0f + (((size_t)(wave*4 + i)*64 + lane) << 3));
    bvL0[i] = b0[((wave*4 + i) << 4) + lm0];
  }
  const int myNt = mem*8 + wave;
  float bv1 = b1[(myNt << 4) + lm0];
  float bv2 = b2[(myNt << 4) + lm0];
  float bv3 = (lm0 < 6) ? b3[lm0] : 0.0f;
  float I9[9], Ii[9];
  #pragma unroll
  for (int i=0;i<9;++i) I9[i] = Imat[i];
  invert3(I9, Ii);

  float X[12];
  #pragma unroll
  for (int c=0;c<12;++c) X[c] = 0.0f;
  if (tid < ROWS){
    const int b = rowbase + tid;
    #pragma unroll
    for (int c=0;c<12;++c){
      float raw = x_t[b*12 + c];
      X[c] = raw;
      if (mem == 0) outX[(size_t)(b*12 + c)*seqlen] = raw;  // stacked[:,:,0]
    }
    build_input(bufA, X, act, b, tid, 1);            // every member builds its copy
  }

  for (int s=0; s<steps; ++s){
    __syncthreads();                                 // input image in bufA ready
    {   // L0: 16(pad32) -> 512, full width, weights in registers
      const int lm = lane & 15, half = lane >> 4;
      const int m0 = lm, m1 = 16 + lm;
      const int sw0 = m0 & 7, sw1 = m1 & 7;
      short8 A0 = *(const short8*)(bufA + m0*512 + ((half ^ sw0) << 3));
      short8 A1 = *(const short8*)(bufA + m1*512 + ((half ^ sw1) << 3));
      #pragma unroll
      for (int i=0;i<4;++i){
        f32x4 a0 = (f32x4)0.0f, a1 = (f32x4)0.0f;
        a0 = __builtin_amdgcn_mfma_f32_16x16x32_bf16(A0, w0r[i], a0, 0, 0, 0);
        a1 = __builtin_amdgcn_mfma_f32_16x16x32_bf16(A1, w0r[i], a1, 0, 0, 0);
        int n = ((wave*4 + i) << 4) + lm;
        #pragma unroll
        for (int reg=0; reg<4; ++reg){
          int r0 = (half << 2) + reg, r1 = 16 + r0;
          float v0 = a0[reg] + bvL0[i]; v0 = (v0 >= 0.0f) ? v0 : 0.01f*v0;
          float v1 = a1[reg] + bvL0[i]; v1 = (v1 >= 0.0f) ? v1 : 0.01f*v1;
          bufB[lds_idx(r0, n)] = f2bf(v0);
          bufB[lds_idx(r1, n)] = f2bf(v1);
        }
      }
    }
    __syncthreads();                                 // bufB(h0) ready, bufA reusable
    layer_ex(bufB, bufA, w1f, bv1, xg1, fl1, (u32)(s+1), mem, lane, wave, tid);  // L1
    layer_ex(bufA, bufB, w2f, bv2, xg2, fl2, (u32)(s+1), mem, lane, wave, tid);  // L2
    if (wave == 0){                                  // L3 + forces + RK4 (all members)
      const int lm = lane & 15, half = lane >> 4;
      const int m0 = lm, m1 = 16 + lm;
      const int sw0 = m0 & 7, sw1 = m1 & 7;
      short8 w3r[16];
      #pragma unroll
      for (int kt=0; kt<16; ++kt)
        w3r[kt] = *(const short8*)(w3f + (((size_t)kt*64 + lane) << 3));
      f32x4 a3_0 = (f32x4)0.0f, a3_1 = (f32x4)0.0f;
      #pragma unroll
      for (int kt=0; kt<16; ++kt){
        int cb = (kt << 2) + half;
        short8 x0 = *(const short8*)(bufB + m0*512 + ((cb ^ sw0) << 3));
        short8 x1 = *(const short8*)(bufB + m1*512 + ((cb ^ sw1) << 3));
        a3_0 = __builtin_amdgcn_mfma_f32_16x16x32_bf16(x0, w3r[kt], a3_0, 0, 0, 0);
        a3_1 = __builtin_amdgcn_mfma_f32_16x16x32_bf16(x1, w3r[kt], a3_1, 0, 0, 0);
      }
      const int c = lm;
      #pragma unroll
      for (int mt=0; mt<2; ++mt){
        #pragma unroll
        for (int reg=0; reg<4; ++reg){
          int rr = (mt << 4) + (half << 2) + reg;
          float fn = ((mt == 0) ? a3_0[reg] : a3_1[reg]) + bv3;
          float f;
          if      (c == 0) f = fn - 0.5f;
          else if (c == 1) f = fn * -0.4f - 10.0f;
          else if (c == 2) f = fn * 0.2f - 0.1f;
          else             f = 0.0f;
          if (c < 6 && mem == 0){
            int b = rowbase + rr;
            outF[(size_t)(b*6 + c)*steps + s] = f;
          }
          if (c < 3) fscr[rr*3 + c] = f;
        }
      }
      asm volatile("s_waitcnt lgkmcnt(0)" ::: "memory");  // fscr visible in-wave
      if (tid < ROWS){
        const int b = rowbase + tid;
        float Fv[3] = { fscr[tid*3], fscr[tid*3+1], fscr[tid*3+2] };
        rk4(X, Fv, I9, Ii);
        if (mem == 0){
          #pragma unroll
          for (int cc=0;cc<12;++cc)
            outX[(size_t)(b*12 + cc)*seqlen + (s+1)] = X[cc];
        }
        if (s + 1 < steps) build_input(bufA, X, act, b, tid, s + 2);
      }
    }
  }
}

extern "C" void kernel_launch(void* const* d_in, const int* in_sizes, int n_in,
                              void* d_out, int out_size, void* d_ws, size_t ws_size,
                              hipStream_t stream)
{
  // setup_inputs() dict order: x_t, act_inps, I_mat, seq_len, W0,b0, W1,b1, W2,b2, W3,b3
  const float* x_t  = (const float*)d_in[0];
  const float* act  = (const float*)d_in[1];
  const float* Imat = (const float*)d_in[2];
  const int*   seqp = (const int*)d_in[3];
  const float* W0   = (const float*)d_in[4];
  const float* b0   = (const float*)d_in[5];
  const float* W1   = (const float*)d_in[6];
  const float* b1   = (const float*)d_in[7];
  const float* W2   = (const float*)d_in[8];
  const float* b2   = (const float*)d_in[9];
  const float* W3   = (const float*)d_in[10];
  const float* b3   = (const float*)d_in[11];
  u16* wfrag = (u16*)d_ws;
  u32* flags = (u32*)((char*)d_ws + WF_TOTAL*2 + 4096);
  u16* xbuf  = (u16*)((char*)d_ws + WF_TOTAL*2 + 8192);

  hipLaunchKernelGGL(wm_repack, dim3((WF_TOTAL + NFLAGS + 255)/256), dim3(256), 0, stream,
                     W0, W1, W2, W3, wfrag);
  hipLaunchKernelGGL(wm_main, dim3(NWG), dim3(THREADS), 0, stream,
                     x_t, act, Imat, seqp, b0, b1, b2, b3, wfrag, flags, xbuf,
                     (float*)d_out);
}

// Round 9
// 5351.010 us; speedup vs baseline: 3.7525x; 3.7525x over previous
//
#include <hip/hip_runtime.h>
#include <stdint.h>

typedef unsigned short u16;
typedef unsigned int   u32;
typedef __attribute__((ext_vector_type(8))) short short8;   // 8 x bf16 fragment (4 VGPRs)
typedef __attribute__((ext_vector_type(4))) float f32x4;    // MFMA accumulator

#define B_TOT   2048
#define HID     512
#define T_FULL  128
#define ROWS    32                 // batch rows per workgroup
#define NWG     (B_TOT / ROWS)     // 64 workgroups
#define THREADS 512                // 8 waves, 2 per SIMD
#define NT      4                  // n-tiles per wave on 512-wide layers

#define W0F_SZ  16384              // 32 ntiles * 64 lanes * 8
#define W1F_SZ  262144             // 32 nt * 16 kt * 64 * 8
#define W3F_SZ  8192               // 1 nt * 16 kt * 64 * 8
#define WF_TOTAL (W0F_SZ + 2*W1F_SZ + W3F_SZ)   // 548864 bf16 elems (~1.07 MB)

__device__ __forceinline__ u16 f2bf(float f){
  u32 u = __float_as_uint(f);
  u32 r = (u + 0x7FFFu + ((u >> 16) & 1u)) >> 16;   // RNE
  return (u16)r;
}

// LDS activation layout: 32 rows x 512 cols bf16, row stride 512 (1024B),
// 16B chunks XOR-swizzled by (row&7) so ds_read_b128 A-fragment reads spread banks.
__device__ __forceinline__ int lds_idx(int m, int k){
  int chunk = k >> 3;
  return m * 512 + ((chunk ^ (m & 7)) << 3) + (k & 7);
}

// ---------------- weight repack: fp32 row-major -> bf16 MFMA B-fragment order -------
// B-frag for 16x16x32: lane l holds B[k = (l>>4)*8 + j][n = l&15], j=0..7 (one dwordx4).
__global__ void wm_repack(const float* __restrict__ W0, const float* __restrict__ W1,
                          const float* __restrict__ W2, const float* __restrict__ W3,
                          u16* __restrict__ wf)
{
  int idx = blockIdx.x * blockDim.x + threadIdx.x;
  if (idx >= WF_TOTAL) return;
  int e = idx;
  if (e < W0F_SZ){                       // W0: 16x512, K padded to 32 with zeros
    int j = e & 7, l = (e >> 3) & 63, nt = e >> 9;
    int k = ((l >> 4) << 3) + j, n = (nt << 4) + (l & 15);
    wf[idx] = (k < 16) ? f2bf(W0[k * HID + n]) : (u16)0;
    return;
  }
  e -= W0F_SZ;
  if (e < W1F_SZ){                       // W1: 512x512
    int j = e & 7, l = (e >> 3) & 63, rest = e >> 9, kt = rest & 15, nt = rest >> 4;
    int k = (kt << 5) + ((l >> 4) << 3) + j, n = (nt << 4) + (l & 15);
    wf[idx] = f2bf(W1[k * HID + n]);
    return;
  }
  e -= W1F_SZ;
  if (e < W1F_SZ){                       // W2: 512x512
    int j = e & 7, l = (e >> 3) & 63, rest = e >> 9, kt = rest & 15, nt = rest >> 4;
    int k = (kt << 5) + ((l >> 4) << 3) + j, n = (nt << 4) + (l & 15);
    wf[idx] = f2bf(W2[k * HID + n]);
    return;
  }
  e -= W1F_SZ;
  {                                      // W3: 512x6, N padded to 16 with zeros
    int j = e & 7, l = (e >> 3) & 63, kt = e >> 9;
    int k = (kt << 5) + ((l >> 4) << 3) + j, n = l & 15;
    wf[idx] = (n < 6) ? f2bf(W3[k * 6 + n]) : (u16)0;
  }
}

// ---------------- dynamics (fp32; __sinf/__cosf: ~1e-6 abs err, well under tol) -----
__device__ __forceinline__ void invert3(const float* a, float* inv){
  float d = a[0]*(a[4]*a[8]-a[5]*a[7]) - a[1]*(a[3]*a[8]-a[5]*a[6]) + a[2]*(a[3]*a[7]-a[4]*a[6]);
  float id = 1.0f / d;
  inv[0]=(a[4]*a[8]-a[5]*a[7])*id; inv[1]=(a[2]*a[7]-a[1]*a[8])*id; inv[2]=(a[1]*a[5]-a[2]*a[4])*id;
  inv[3]=(a[5]*a[6]-a[3]*a[8])*id; inv[4]=(a[0]*a[8]-a[2]*a[6])*id; inv[5]=(a[2]*a[3]-a[0]*a[5])*id;
  inv[6]=(a[3]*a[7]-a[4]*a[6])*id; inv[7]=(a[1]*a[6]-a[0]*a[7])*id; inv[8]=(a[0]*a[4]-a[1]*a[3])*id;
}

__device__ __forceinline__ void derivs(const float* x, const float* Fv,
                                       const float* I9, const float* Ii, float* dx)
{
  float V0=x[3], V1=x[4], V2=x[5];
  float phi=x[6], th=x[7], psi=x[8];
  float w0=x[9], w1=x[10], w2=x[11];
  float sph=__sinf(phi), cph=__cosf(phi);
  float sth=__sinf(th),  cth=__cosf(th);
  float sps=__sinf(psi), cps=__cosf(psi);
  float r00=cth*cps, r01=sph*sth*cps - cph*sps, r02=cph*sth*cps + sph*sps;
  float r10=cth*sps, r11=sph*sth*sps + cph*cps, r12=cph*sth*sps - sph*cps;
  float r20=-sth,    r21=sph*cth,               r22=cph*cth;
  dx[0]=r00*V0+r01*V1+r02*V2;
  dx[1]=r10*V0+r11*V1+r12*V2;
  dx[2]=r20*V0+r21*V1+r22*V2;
  const float invm = 1.0f/1.5f;
  dx[3]=Fv[0]*invm - (w1*V2 - w2*V1);
  dx[4]=Fv[1]*invm - (w2*V0 - w0*V2);
  dx[5]=Fv[2]*invm - (w0*V1 - w1*V0);
  float tth = sth / cth;
  float rc  = 1.0f / fmaxf(cth, 1e-6f);
  dx[6]= w0 + sph*tth*w1 + cph*tth*w2;
  dx[7]=      cph*w1     - sph*w2;
  dx[8]=      sph*rc*w1  + cph*rc*w2;
  float Iw0=I9[0]*w0+I9[1]*w1+I9[2]*w2;
  float Iw1=I9[3]*w0+I9[4]*w1+I9[5]*w2;
  float Iw2=I9[6]*w0+I9[7]*w1+I9[8]*w2;
  float c0=w1*Iw2-w2*Iw1, c1=w2*Iw0-w0*Iw2, c2=w0*Iw1-w1*Iw0;
  dx[9] = -(Ii[0]*c0+Ii[1]*c1+Ii[2]*c2);
  dx[10]= -(Ii[3]*c0+Ii[4]*c1+Ii[5]*c2);
  dx[11]= -(Ii[6]*c0+Ii[7]*c1+Ii[8]*c2);
}

__device__ __forceinline__ void rk4(float* X, const float* Fv, const float* I9, const float* Ii){
  float k1[12],k2[12],k3[12],k4[12],xt[12];
  derivs(X,Fv,I9,Ii,k1);
  #pragma unroll
  for (int c=0;c<12;++c) xt[c]=X[c]+0.005f*k1[c];
  derivs(xt,Fv,I9,Ii,k2);
  #pragma unroll
  for (int c=0;c<12;++c) xt[c]=X[c]+0.005f*k2[c];
  derivs(xt,Fv,I9,Ii,k3);
  #pragma unroll
  for (int c=0;c<12;++c) xt[c]=X[c]+0.01f*k3[c];
  derivs(xt,Fv,I9,Ii,k4);
  #pragma unroll
  for (int c=0;c<12;++c) X[c]+=(0.01f/6.0f)*(k1[c]+2.0f*k2[c]+2.0f*k3[c]+k4[c]);
}

// normalized MLP input: [x*NORM (12, tail 6 are zero), (act-1500)/500 (4), zero pad to 32]
__device__ __forceinline__ void build_input(u16* bufA, const float* X,
                                            const float* __restrict__ act,
                                            int b, int r, int t)
{
  float vin[16];
  vin[0]=X[0]*1.2732395447351628f;
  vin[1]=X[1]*0.5f;
  vin[2]=X[2]*1.2732395447351628f;
  vin[3]=X[3]*0.1f;
  vin[4]=X[4]*0.016666666666666666f;
  vin[5]=X[5]*0.016666666666666666f;
  #pragma unroll
  for (int c=6;c<12;++c) vin[c]=0.0f;
  #pragma unroll
  for (int a=0;a<4;++a)
    vin[12+a] = (act[(size_t)(b*4+a)*T_FULL + t] - 1500.0f) * 0.002f;
  #pragma unroll
  for (int p=0;p<16;++p){
    u32 pack = 0u;
    if (p < 8) pack = (u32)f2bf(vin[2*p]) | ((u32)f2bf(vin[2*p+1]) << 16);
    ((u32*)bufA)[lds_idx(r, 2*p) >> 1] = pack;   // (k&7) even -> dword aligned
  }
}

// One MLP layer: bufIn (A, swizzled LDS) @ Wfrag (+bias, leaky) -> bufOut.
// 8 waves x 4 n-tiles = 512 cols; 2 m-tiles cover 32 rows.
// KT=16: 4 blocks of 4 kt, double-block register buffer (r4 structure).
template<int KT>
__device__ __forceinline__ void do_layer(const u16* __restrict__ bufIn,
                                         const u16* __restrict__ wfrag,
                                         const float* __restrict__ bias,
                                         u16* __restrict__ bufOut,
                                         int lane, int ntb)
{
  const int lm = lane & 15, half = lane >> 4;
  const int m0 = lm, m1 = 16 + lm;
  const int sw0 = m0 & 7, sw1 = m1 & 7;
  f32x4 acc0[NT], acc1[NT];
  #pragma unroll
  for (int i=0;i<NT;++i){ acc0[i]=(f32x4)0.0f; acc1[i]=(f32x4)0.0f; }

  const u16* wbase = wfrag + (((size_t)ntb*KT*64 + lane) << 3);

  if constexpr (KT == 1){
    short8 A0 = *(const short8*)(bufIn + m0*512 + ((half ^ sw0) << 3));
    short8 A1 = *(const short8*)(bufIn + m1*512 + ((half ^ sw1) << 3));
    short8 Bf[NT];
    #pragma unroll
    for (int i=0;i<NT;++i)
      Bf[i] = *(const short8*)(wbase + ((size_t)i << 9));
    #pragma unroll
    for (int i=0;i<NT;++i){
      acc0[i] = __builtin_amdgcn_mfma_f32_16x16x32_bf16(A0, Bf[i], acc0[i], 0, 0, 0);
      acc1[i] = __builtin_amdgcn_mfma_f32_16x16x32_bf16(A1, Bf[i], acc1[i], 0, 0, 0);
    }
  } else {
    static_assert(KT == 16, "KT must be 1 or 16");
    short8 Bf[2][4][NT];                       // [block parity][kt in block][nt]
    #pragma unroll
    for (int j=0;j<4;++j)
      #pragma unroll
      for (int i=0;i<NT;++i)
        Bf[0][j][i] = *(const short8*)(wbase + ((size_t)(i*KT + j) << 9));
    #pragma unroll
    for (int blk=0; blk<4; ++blk){
      const int cur = blk & 1, nxt = cur ^ 1;
      if (blk < 3){                            // issue block blk+1's 16 loads first
        #pragma unroll
        for (int j=0;j<4;++j)
          #pragma unroll
          for (int i=0;i<NT;++i)
            Bf[nxt][j][i] = *(const short8*)(wbase + ((size_t)(i*KT + blk*4 + 4 + j) << 9));
      }
      short8 A0[4], A1[4];
      #pragma unroll
      for (int j=0;j<4;++j){
        const int cb = ((blk*4 + j) << 2) + half;
        A0[j] = *(const short8*)(bufIn + m0*512 + ((cb ^ sw0) << 3));
        A1[j] = *(const short8*)(bufIn + m1*512 + ((cb ^ sw1) << 3));
      }
      #pragma unroll
      for (int j=0;j<4;++j)
        #pragma unroll
        for (int i=0;i<NT;++i){
          acc0[i] = __builtin_amdgcn_mfma_f32_16x16x32_bf16(A0[j], Bf[cur][j][i], acc0[i], 0, 0, 0);
          acc1[i] = __builtin_amdgcn_mfma_f32_16x16x32_bf16(A1[j], Bf[cur][j][i], acc1[i], 0, 0, 0);
        }
    }
  }
  // epilogue: +bias, leaky, bf16, store in swizzled A-layout for next layer
  #pragma unroll
  for (int i=0;i<NT;++i){
    int n = ((ntb + i) << 4) + lm;
    float bv = bias[n];
    #pragma unroll
    for (int reg=0; reg<4; ++reg){
      int r0 = (half << 2) + reg, r1 = 16 + r0;
      float v0 = acc0[i][reg] + bv; v0 = (v0 >= 0.0f) ? v0 : 0.01f*v0;
      float v1 = acc1[i][reg] + bv; v1 = (v1 >= 0.0f) ? v1 : 0.01f*v1;
      bufOut[lds_idx(r0, n)] = f2bf(v0);
      bufOut[lds_idx(r1, n)] = f2bf(v1);
    }
  }
}

__global__ __launch_bounds__(THREADS, 2)
void wm_main(const float* __restrict__ x_t, const float* __restrict__ act,
             const float* __restrict__ Imat, const int* __restrict__ seqlen_p,
             const float* __restrict__ b0, const float* __restrict__ b1,
             const float* __restrict__ b2, const float* __restrict__ b3,
             const u16* __restrict__ wf, float* __restrict__ out)
{
  __shared__ u16 bufA[16384];            // 32 KB
  __shared__ u16 bufB[16384];            // 32 KB
  __shared__ float xstage[32*12*32];     // 48 KB: 32 steps of X, [(row*12+c)*32 + slot]
  __shared__ float fstage[32*6*32];      // 24 KB: 32 steps of F, [(row*6+c)*32 + slot]
  float* fscr = (float*)(bufA + 256);    // RK4 force scratch (3ch), dead region in tail

  const int tid  = threadIdx.x;
  const int lane = tid & 63;
  const int wave = tid >> 6;
  const int ntb  = wave * NT;            // 4 n-tiles per wave
  const int rowbase = blockIdx.x * ROWS;
  const int steps = seqlen_p[0] - 1;     // 127
  const int seqlen = steps + 1;

  const u16* w0f = wf;
  const u16* w1f = wf + W0F_SZ;
  const u16* w2f = w1f + W1F_SZ;
  const u16* w3f = w2f + W1F_SZ;

  float* outF = out;                                   // (B, 6, steps) fp32
  float* outX = out + (size_t)B_TOT * 6 * steps;       // (B, 12, seqlen) fp32

  float X[12];                           // persistent per-lane state (rows on wave 0)
  if (tid < ROWS){
    const int b = rowbase + tid;
    #pragma unroll
    for (int c=0;c<12;++c){
      float raw = x_t[b*12 + c];
      X[c] = raw;
      outX[(size_t)(b*12 + c)*seqlen] = raw;           // stacked[:,:,0] = x_t (once)
    }
    build_input(bufA, X, act, b, tid, 1);              // step 0 uses act t=1
  }

  for (int s=0; s<steps; ++s){
    __syncthreads();                                   // input in bufA ready
    do_layer<1 >(bufA, w0f, b0, bufB, lane, ntb);      // L0: 16(pad32) -> 512
    __syncthreads();
    do_layer<16>(bufB, w1f, b1, bufA, lane, ntb);      // L1: 512 -> 512
    __syncthreads();
    do_layer<16>(bufA, w2f, b2, bufB, lane, ntb);      // L2: 512 -> 512
    __syncthreads();
    const int slot = s & 31;
    if (wave == 0){                                    // L3: 512 -> 6 (+forces) + RK4
      const int lm = lane & 15, half = lane >> 4;
      const int m0 = lm, m1 = 16 + lm;
      const int sw0 = m0 & 7, sw1 = m1 & 7;
      short8 w3r[16];
      #pragma unroll
      for (int kt=0; kt<16; ++kt)                      // 16 loads in flight up front
        w3r[kt] = *(const short8*)(w3f + (((size_t)kt*64 + lane) << 3));
      f32x4 a3_0 = (f32x4)0.0f, a3_1 = (f32x4)0.0f;
      #pragma unroll
      for (int kt=0; kt<16; ++kt){
        int cb = (kt << 2) + half;
        short8 x0 = *(const short8*)(bufB + m0*512 + ((cb ^ sw0) << 3));
        short8 x1 = *(const short8*)(bufB + m1*512 + ((cb ^ sw1) << 3));
        a3_0 = __builtin_amdgcn_mfma_f32_16x16x32_bf16(x0, w3r[kt], a3_0, 0, 0, 0);
        a3_1 = __builtin_amdgcn_mfma_f32_16x16x32_bf16(x1, w3r[kt], a3_1, 0, 0, 0);
      }
      const int c = lm;
      float bv = (c < 6) ? b3[c] : 0.0f;
      #pragma unroll
      for (int mt=0; mt<2; ++mt){
        #pragma unroll
        for (int reg=0; reg<4; ++reg){
          int rr = (mt << 4) + (half << 2) + reg;
          float fn = ((mt == 0) ? a3_0[reg] : a3_1[reg]) + bv;
          float f;
          if      (c == 0) f = fn - 0.5f;
          else if (c == 1) f = fn * -0.4f - 10.0f;
          else if (c == 2) f = fn * 0.2f - 0.1f;
          else             f = 0.0f;
          if (c < 6) fstage[(rr*6 + c)*32 + slot] = f;  // staged, dumped every 32 steps
          if (c < 3) fscr[rr*3 + c] = f;
        }
      }
      // fscr writer and reader are both wave 0: in-wave LDS drain replaces a barrier
      asm volatile("s_waitcnt lgkmcnt(0)" ::: "memory");
      if (tid < ROWS){
        const int b = rowbase + tid;
        float I9[9], Ii[9];
        #pragma unroll
        for (int i=0;i<9;++i) I9[i] = Imat[i];         // L2-hot broadcast
        invert3(I9, Ii);
        float Fv[3] = { fscr[tid*3], fscr[tid*3+1], fscr[tid*3+2] };
        rk4(X, Fv, I9, Ii);
        #pragma unroll
        for (int cc=0;cc<12;++cc)
          xstage[(tid*12 + cc)*32 + slot] = X[cc];     // staged
        if (s + 1 < steps) build_input(bufA, X, act, b, tid, s + 2);
      }
    }
    // ---- coalesced dump every 32 steps (and at the end): 128B-aligned runs ----
    if (slot == 31 || s == steps - 1){
      __syncthreads();                                 // stage buffers complete
      const int cnt = slot + 1;                        // steps in this batch
      const int sBase = s - slot;                      // global step of slot 0
      const int so = tid & 31;                         // this thread's slot
      if (so < cnt){
        for (int i = tid; i < 384*32; i += THREADS){   // X: 384 (row,c) pairs
          int pair = i >> 5;
          int row = pair / 12, c = pair - row*12;
          outX[(size_t)((rowbase + row)*12 + c)*seqlen + sBase + 1 + so]
              = xstage[pair*32 + so];
        }
        for (int i = tid; i < 192*32; i += THREADS){   // F: 192 (row,c) pairs
          int pair = i >> 5;
          int row = pair / 6, c = pair - row*6;
          outF[(size_t)((rowbase + row)*6 + c)*steps + sBase + so]
              = fstage[pair*32 + so];
        }
      }
    }
  }
}

extern "C" void kernel_launch(void* const* d_in, const int* in_sizes, int n_in,
                              void* d_out, int out_size, void* d_ws, size_t ws_size,
                              hipStream_t stream)
{
  // setup_inputs() dict order: x_t, act_inps, I_mat, seq_len, W0,b0, W1,b1, W2,b2, W3,b3
  const float* x_t  = (const float*)d_in[0];
  const float* act  = (const float*)d_in[1];
  const float* Imat = (const float*)d_in[2];
  const int*   seqp = (const int*)d_in[3];
  const float* W0   = (const float*)d_in[4];
  const float* b0   = (const float*)d_in[5];
  const float* W1   = (const float*)d_in[6];
  const float* b1   = (const float*)d_in[7];
  const float* W2   = (const float*)d_in[8];
  const float* b2   = (const float*)d_in[9];
  const float* W3   = (const float*)d_in[10];
  const float* b3   = (const float*)d_in[11];
  u16* wfrag = (u16*)d_ws;

  hipLaunchKernelGGL(wm_repack, dim3((WF_TOTAL + 255)/256), dim3(256), 0, stream,
                     W0, W1, W2, W3, wfrag);
  hipLaunchKernelGGL(wm_main, dim3(NWG), dim3(THREADS), 0, stream,
                     x_t, act, Imat, seqp, b0, b1, b2, b3, wfrag, (float*)d_out);
}